// Round 6
// baseline (666.894 us; speedup 1.0000x reference)
//
#include <hip/hip_runtime.h>
#include <stdint.h>

#define T_TOK 8192
#define DDIM  1024
#define FDIM  4096
#define NEXP  8
#define BM 128
#define BK 64
#define MAX_MT (T_TOK / BM + NEXP)   // worst-case sum of per-expert M-tiles = 72

typedef __attribute__((ext_vector_type(8))) short bf16x8;
typedef __attribute__((ext_vector_type(8))) unsigned short u16x8;
typedef __attribute__((ext_vector_type(4))) float f32x4;

__device__ __forceinline__ unsigned short f2bf(float f) {
    union { float f; unsigned u; } v; v.f = f;
    unsigned u = v.u;
    u += 0x7fffu + ((u >> 16) & 1u);   // round-to-nearest-even
    return (unsigned short)(u >> 16);
}

__device__ __forceinline__ void async16(const void* g, void* l) {
    __builtin_amdgcn_global_load_lds(
        (const __attribute__((address_space(1))) unsigned int*)g,
        (__attribute__((address_space(3))) unsigned int*)l, 16, 0, 0);
}

// ============ init: zero meta + build WrT[8][1024] (replaces memset) =======
__global__ __launch_bounds__(256) void init_kernel(
    const float* __restrict__ Wr, float* __restrict__ WrT, int* __restrict__ meta) {
    int idx = blockIdx.x * 256 + threadIdx.x;   // 32 blocks x 256 = 8192
    if (idx < 16) meta[idx] = 0;
    float v = Wr[idx];                          // Wr[d][e], d=idx>>3, e=idx&7
    WrT[(idx & 7) * DDIM + (idx >> 3)] = v;
}

// ==== fused prep: blockIdx&3 == 0 router, 1 W1-T, 2 W2-T, 3 zero-y ====
__global__ __launch_bounds__(256) void prep(
    const float* __restrict__ x, const float* __restrict__ WrT, const float* __restrict__ br,
    const float* __restrict__ lng, const float* __restrict__ lnb,
    const float* __restrict__ W1, const float* __restrict__ W2,
    unsigned short* __restrict__ xn, unsigned short* __restrict__ W1t,
    unsigned short* __restrict__ W2t, float* __restrict__ gate,
    int* __restrict__ expert, int* __restrict__ counts, float* __restrict__ y) {
    __shared__ float smem[64 * 65];
    int b = blockIdx.x, tid = threadIdx.x;
    int r4 = b & 3, q = b >> 2;

    if (r4 == 3) {
        // zero y: 8192 blocks x 256 thr x float4 = 32 MB
        float4 z = make_float4(0.f, 0.f, 0.f, 0.f);
        ((float4*)y)[(size_t)q * 256 + tid] = z;
        return;
    }
    if (r4 != 0) {
        // ---------- transpose + fp32->bf16 ----------
        const float* src; unsigned short* dst; int R, C, e, c0, r0;
        if (r4 == 1) {                  // W1 [E][1024][4096] -> W1t [E][4096][1024]
            R = DDIM; C = FDIM;
            e = q >> 10;
            c0 = (q & 63) * 64; r0 = ((q >> 6) & 15) * 64;
            src = W1; dst = W1t;
        } else {                        // W2 [E][4096][1024] -> W2t [E][1024][4096]
            R = FDIM; C = DDIM;
            e = q >> 10;
            c0 = (q & 15) * 64; r0 = ((q >> 4) & 63) * 64;
            src = W2; dst = W2t;
        }
        const float* s = src + (size_t)e * R * C;
        unsigned short* d = dst + (size_t)e * R * C;
        float (*tile)[65] = (float(*)[65])smem;
        int lr = tid >> 4, lc = (tid & 15) * 4;
#pragma unroll
        for (int i = 0; i < 4; i++) {
            float4 v = *(const float4*)&s[(size_t)(r0 + lr + i * 16) * C + c0 + lc];
            tile[lr + i * 16][lc + 0] = v.x;
            tile[lr + i * 16][lc + 1] = v.y;
            tile[lr + i * 16][lc + 2] = v.z;
            tile[lr + i * 16][lc + 3] = v.w;
        }
        __syncthreads();
#pragma unroll
        for (int i = 0; i < 2; i++) {
            int ix = tid + i * 256;
            int drow = ix >> 3, seg = ix & 7;
            u16x8 o;
#pragma unroll
            for (int j = 0; j < 8; j++) o[j] = f2bf(tile[seg * 8 + j][drow]);
            *(u16x8*)&d[(size_t)(c0 + drow) * R + r0 + seg * 8] = o;
        }
        return;
    }

    // ---------- router + layernorm ----------
    int t = q;
    const float* xrow = x + (size_t)t * DDIM;
    float4 xv = ((const float4*)xrow)[tid];
    float s  = xv.x + xv.y + xv.z + xv.w;
    float sq = xv.x * xv.x + xv.y * xv.y + xv.z * xv.z + xv.w * xv.w;
    ((float2*)smem)[tid] = make_float2(s, sq);

    // logits: 32 lanes per expert, lane-strided dims (coalesced scalar loads)
    int e = tid >> 5, l32 = tid & 31;
    const float* wrow = WrT + e * DDIM + l32;
    const float* xp = xrow + l32;
    float a0 = 0, a1 = 0, a2 = 0, a3 = 0;
#pragma unroll
    for (int j = 0; j < 32; j += 4) {
        a0 += xp[32 * j]       * wrow[32 * j];
        a1 += xp[32 * (j + 1)] * wrow[32 * (j + 1)];
        a2 += xp[32 * (j + 2)] * wrow[32 * (j + 2)];
        a3 += xp[32 * (j + 3)] * wrow[32 * (j + 3)];
    }
    float acc = (a0 + a1) + (a2 + a3);
#pragma unroll
    for (int o = 16; o > 0; o >>= 1) acc += __shfl_down(acc, o, 32);
    if ((tid & 31) == 0) smem[512 + e] = acc;
    __syncthreads();

    if (tid < 64) {
        float2 p0 = ((float2*)smem)[tid];
        float2 p1 = ((float2*)smem)[tid + 64];
        float2 p2 = ((float2*)smem)[tid + 128];
        float2 p3 = ((float2*)smem)[tid + 192];
        float ss = (p0.x + p1.x) + (p2.x + p3.x);
        float qq = (p0.y + p1.y) + (p2.y + p3.y);
#pragma unroll
        for (int o = 32; o > 0; o >>= 1) {
            ss += __shfl_down(ss, o);
            qq += __shfl_down(qq, o);
        }
        if (tid == 0) {
            float mu = ss * (1.f / DDIM);
            float var = qq * (1.f / DDIM) - mu * mu;
            float rstd = rsqrtf(var + 1e-5f);
            int best = 0; float bl = -3.4e38f;
            float L[8];
            for (int k = 0; k < 8; k++) {
                float l = smem[512 + k] + br[k];
                L[k] = l;
                if (l > bl) { bl = l; best = k; }   // strict > == jnp.argmax first-max
            }
            float den = 0;
            for (int k = 0; k < 8; k++) den += __expf(L[k] - bl);
            gate[t] = 1.f / den;
            expert[t] = best;
            atomicAdd(&counts[best], 1);
            smem[520] = mu; smem[521] = rstd;
        }
    }
    __syncthreads();
    float mu = smem[520], rstd = smem[521];
    float4 gg = ((const float4*)lng)[tid];
    float4 bb = ((const float4*)lnb)[tid];
    ushort4 o;
    o.x = f2bf((xv.x - mu) * rstd * gg.x + bb.x);
    o.y = f2bf((xv.y - mu) * rstd * gg.y + bb.y);
    o.z = f2bf((xv.z - mu) * rstd * gg.z + bb.z);
    o.w = f2bf((xv.w - mu) * rstd * gg.w + bb.w);
    *(ushort4*)(xn + (size_t)t * DDIM + tid * 4) = o;
}

// ---------------- scatter tokens into per-expert lists (scan folded in) ----
__global__ __launch_bounds__(256) void scatter_perm(
    const int* __restrict__ expert, const int* __restrict__ counts,
    int* __restrict__ fill, int* __restrict__ perm) {
    __shared__ int offs_s[NEXP];
    if (threadIdx.x < NEXP) {
        int o = 0;
        for (int i = 0; i < (int)threadIdx.x; i++) o += counts[i];
        offs_s[threadIdx.x] = o;
    }
    __syncthreads();
    int t = blockIdx.x * 256 + threadIdx.x;
    int e = expert[t];
    int p = atomicAdd(&fill[e], 1);
    perm[offs_s[e] + p] = t;
}

// ---------------- grouped GEMM: 128x128, BK=64, xor-swizzled LDS ----------
// MODE 0: h_perm = relu(xn[perm] @ W1t[e]^T + b1[e])   K=1024, grid.y = 32
// MODE 1: y[perm] += half-K (h_perm @ W2t[e]^T [+b2])*gate  split-K=2,
//         grid.y = 16 (8 n-tiles x 2 k-halves), fp32 atomicAdd epilogue
template <int MODE>
__global__ __launch_bounds__(256) void gemm_grouped(
    const unsigned short* __restrict__ A, const unsigned short* __restrict__ Bt,
    const float* __restrict__ bias, unsigned short* __restrict__ Hout,
    float* __restrict__ Yout, const float* __restrict__ gate,
    const int* __restrict__ perm, const int* __restrict__ counts,
    int K, int N) {
    int rem = blockIdx.x;
    int e, off = 0, cnt = 0; bool found = false;
    for (e = 0; e < NEXP; e++) {
        cnt = counts[e];
        int mt = (cnt + (BM - 1)) >> 7;
        if (rem < mt) { found = true; break; }
        rem -= mt; off += cnt;
    }
    if (!found) return;
    int mbase = rem << 7;
    int mrem = cnt - mbase;
    int n0, kbase, kend, kh;
    if (MODE == 0) {
        n0 = blockIdx.y << 7; kbase = 0; kend = K; kh = 0;
    } else {
        n0 = (blockIdx.y >> 1) << 7;
        kh = blockIdx.y & 1;
        kbase = kh * (K >> 1); kend = kbase + (K >> 1);
    }

    __shared__ __align__(16) unsigned short Alds[BM * BK];   // 16 KB
    __shared__ __align__(16) unsigned short Blds[128 * BK];  // 16 KB

    int tid = threadIdx.x;
    int lane = tid & 63, wave = tid >> 6;
    int grow = lane >> 3;         // 0..7: row within 8-row chunk
    int seg  = lane & 7;          // 0..7: LDS 16B slot within 128B row
    int gseg = seg ^ grow;        // xor-swizzled global k-chunk

    const unsigned short* ag[4];
    unsigned short* al[4];
    const unsigned short* bg[4];
    unsigned short* bl[4];
#pragma unroll
    for (int p = 0; p < 4; p++) {
        int r = p * 32 + wave * 8 + grow;
        int rr = (r < mrem) ? r : 0;
        int t = (MODE == 0) ? perm[off + mbase + rr] : (off + mbase + rr);
        ag[p] = A + (size_t)t * K + gseg * 8;
        al[p] = &Alds[(p * 32 + wave * 8) * BK];   // wave-uniform base
        bg[p] = Bt + ((size_t)e * N + n0 + r) * K + gseg * 8;
        bl[p] = &Blds[(p * 32 + wave * 8) * BK];
    }

    int wr = (wave >> 1) * 64, wc = (wave & 1) * 64;
    int q = lane >> 4, l16 = lane & 15;
    int sx = l16 & 7;             // row&7 for all frag rows this lane touches

    f32x4 acc[4][4] = {};

    for (int k0 = kbase; k0 < kend; k0 += BK) {
#pragma unroll
        for (int p = 0; p < 4; p++) async16(ag[p] + k0, al[p]);
#pragma unroll
        for (int p = 0; p < 4; p++) async16(bg[p] + k0, bl[p]);
        __syncthreads();
#pragma unroll
        for (int kk = 0; kk < 2; kk++) {
            int slot = ((kk * 4 + q) ^ sx) * 8;
            bf16x8 af[4], bfr[4];
#pragma unroll
            for (int i = 0; i < 4; i++)
                af[i] = *(const bf16x8*)&Alds[(wr + i * 16 + l16) * BK + slot];
#pragma unroll
            for (int j = 0; j < 4; j++)
                bfr[j] = *(const bf16x8*)&Blds[(wc + j * 16 + l16) * BK + slot];
#pragma unroll
            for (int i = 0; i < 4; i++)
#pragma unroll
                for (int j = 0; j < 4; j++)
                    acc[i][j] = __builtin_amdgcn_mfma_f32_16x16x32_bf16(af[i], bfr[j], acc[i][j], 0, 0, 0);
        }
        __syncthreads();
    }

    // epilogue: D layout col = lane&15, row = quad*4 + reg (m89/m91)
    float bs[4];
#pragma unroll
    for (int j = 0; j < 4; j++) bs[j] = bias[(size_t)e * N + n0 + wc + j * 16 + l16];
#pragma unroll
    for (int i = 0; i < 4; i++) {
#pragma unroll
        for (int r = 0; r < 4; r++) {
            int lrow = wr + i * 16 + q * 4 + r;
            if (lrow < mrem) {
                if (MODE == 0) {
                    unsigned short* hp = Hout + (size_t)(off + mbase + lrow) * N + n0 + wc + l16;
#pragma unroll
                    for (int j = 0; j < 4; j++) {
                        float v = acc[i][j][r] + bs[j];
                        hp[j * 16] = f2bf(fmaxf(v, 0.f));
                    }
                } else {
                    int t = perm[off + mbase + lrow];
                    float gt = gate[t];
                    float* yp = Yout + (size_t)t * N + n0 + wc + l16;
#pragma unroll
                    for (int j = 0; j < 4; j++) {
                        float v = (acc[i][j][r] + (kh ? 0.f : bs[j])) * gt;
                        atomicAdd(&yp[j * 16], v);
                    }
                }
            }
        }
    }
}

extern "C" void kernel_launch(void* const* d_in, const int* in_sizes, int n_in,
                              void* d_out, int out_size, void* d_ws, size_t ws_size,
                              hipStream_t stream) {
    const float* x   = (const float*)d_in[0];
    const float* Wr  = (const float*)d_in[1];
    const float* br  = (const float*)d_in[2];
    const float* lng = (const float*)d_in[3];
    const float* lnb = (const float*)d_in[4];
    const float* W1  = (const float*)d_in[5];
    const float* b1  = (const float*)d_in[6];
    const float* W2  = (const float*)d_in[7];
    const float* b2  = (const float*)d_in[8];
    float* out = (float*)d_out;

    char* ws = (char*)d_ws;
    size_t o = 0;
    unsigned short* W1t = (unsigned short*)(ws + o); o += (size_t)NEXP * DDIM * FDIM * 2;  // [E][F][D]
    unsigned short* W2t = (unsigned short*)(ws + o); o += (size_t)NEXP * DDIM * FDIM * 2;  // [E][D][F]
    unsigned short* xn  = (unsigned short*)(ws + o); o += (size_t)T_TOK * DDIM * 2;        // [T][D]
    unsigned short* h   = (unsigned short*)(ws + o); o += (size_t)T_TOK * FDIM * 2;        // [Tperm][F]
    float* gate = (float*)(ws + o); o += (size_t)T_TOK * 4;
    float* WrT  = (float*)(ws + o); o += (size_t)NEXP * DDIM * 4;                          // [E][D]
    int* expert = (int*)(ws + o);   o += (size_t)T_TOK * 4;
    int* perm   = (int*)(ws + o);   o += (size_t)T_TOK * 4;
    int* meta   = (int*)(ws + o);   // counts[8], fill[8]
    int* counts = meta;
    int* fill   = meta + 8;

    init_kernel<<<32, 256, 0, stream>>>(Wr, WrT, meta);
    prep<<<4 * T_TOK, 256, 0, stream>>>(x, WrT, br, lng, lnb, W1, W2,
                                        xn, W1t, W2t, gate, expert, counts, out);
    scatter_perm<<<T_TOK / 256, 256, 0, stream>>>(expert, counts, fill, perm);
    gemm_grouped<0><<<dim3(MAX_MT, FDIM / 128), 256, 0, stream>>>(
        xn, W1t, b1, h, nullptr, nullptr, perm, counts, DDIM, FDIM);
    gemm_grouped<1><<<dim3(MAX_MT, (DDIM / 128) * 2), 256, 0, stream>>>(
        h, W2t, b2, nullptr, out, gate, perm, counts, FDIM, DDIM);
}

// Round 7
// 620.064 us; speedup vs baseline: 1.0755x; 1.0755x over previous
//
#include <hip/hip_runtime.h>
#include <stdint.h>

#define T_TOK 8192
#define DDIM  1024
#define FDIM  4096
#define NEXP  8
#define BM 128
#define BK 64
#define MAX_MT (T_TOK / BM + NEXP)       // 72 worst-case M-tile slots
#define G0_TILES (MAX_MT * (FDIM / 128)) // 2304 GEMM0 blocks
#define W2_TILES 8192                    // 64x64 transpose tiles for W2

typedef __attribute__((ext_vector_type(8))) short bf16x8;
typedef __attribute__((ext_vector_type(8))) unsigned short u16x8;
typedef __attribute__((ext_vector_type(4))) float f32x4;

__device__ __forceinline__ unsigned short f2bf(float f) {
    union { float f; unsigned u; } v; v.f = f;
    unsigned u = v.u;
    u += 0x7fffu + ((u >> 16) & 1u);   // round-to-nearest-even
    return (unsigned short)(u >> 16);
}

__device__ __forceinline__ void async16(const void* g, void* l) {
    __builtin_amdgcn_global_load_lds(
        (const __attribute__((address_space(1))) unsigned int*)g,
        (__attribute__((address_space(3))) unsigned int*)l, 16, 0, 0);
}

// shared 64x64 fp32 transpose tile -> bf16 store (needs 16.6 KB LDS as float[64][65])
__device__ __forceinline__ void transpose_tile64(
    float* smem, const float* __restrict__ src, unsigned short* __restrict__ dst,
    int R, int C, int e, int r0, int c0, int tid) {
    const float* s = src + (size_t)e * R * C;
    unsigned short* d = dst + (size_t)e * R * C;
    float (*tile)[65] = (float(*)[65])smem;
    int lr = tid >> 4, lc = (tid & 15) * 4;
#pragma unroll
    for (int i = 0; i < 4; i++) {
        float4 v = *(const float4*)&s[(size_t)(r0 + lr + i * 16) * C + c0 + lc];
        tile[lr + i * 16][lc + 0] = v.x;
        tile[lr + i * 16][lc + 1] = v.y;
        tile[lr + i * 16][lc + 2] = v.z;
        tile[lr + i * 16][lc + 3] = v.w;
    }
    __syncthreads();
#pragma unroll
    for (int i = 0; i < 2; i++) {
        int ix = tid + i * 256;
        int drow = ix >> 3, seg = ix & 7;
        u16x8 o;
#pragma unroll
        for (int j = 0; j < 8; j++) o[j] = f2bf(tile[seg * 8 + j][drow]);
        *(u16x8*)&d[(size_t)(c0 + drow) * R + r0 + seg * 8] = o;
    }
}

// ============ init: zero meta + build WrT[8][1024] =========================
__global__ __launch_bounds__(256) void init_kernel(
    const float* __restrict__ Wr, float* __restrict__ WrT, int* __restrict__ meta) {
    int idx = blockIdx.x * 256 + threadIdx.x;   // 32 blocks x 256 = 8192
    if (idx < 16) meta[idx] = 0;
    float v = Wr[idx];                          // Wr[d][e], d=idx>>3, e=idx&7
    WrT[(idx & 7) * DDIM + (idx >> 3)] = v;
}

// ==== prep: blockIdx&1 == 0 -> router+LN (q<8192), 1 -> W1-transpose =======
__global__ __launch_bounds__(256) void prep(
    const float* __restrict__ x, const float* __restrict__ WrT, const float* __restrict__ br,
    const float* __restrict__ lng, const float* __restrict__ lnb,
    const float* __restrict__ W1,
    unsigned short* __restrict__ xn, unsigned short* __restrict__ W1t,
    float* __restrict__ gate, int* __restrict__ expert, int* __restrict__ counts) {
    __shared__ float smem[64 * 65];
    int b = blockIdx.x, tid = threadIdx.x;
    int r2 = b & 1, q = b >> 1;

    if (r2 == 1) {
        // W1 [E][1024][4096] -> W1t [E][4096][1024]; 1024 tiles/expert
        int e = q >> 10;
        int c0 = (q & 63) * 64, r0 = ((q >> 6) & 15) * 64;
        transpose_tile64(smem, W1, W1t, DDIM, FDIM, e, r0, c0, tid);
        return;
    }

    // ---------- router + layernorm ----------
    int t = q;
    const float* xrow = x + (size_t)t * DDIM;
    float4 xv = ((const float4*)xrow)[tid];
    float s  = xv.x + xv.y + xv.z + xv.w;
    float sq = xv.x * xv.x + xv.y * xv.y + xv.z * xv.z + xv.w * xv.w;
    ((float2*)smem)[tid] = make_float2(s, sq);

    int e = tid >> 5, l32 = tid & 31;
    const float* wrow = WrT + e * DDIM + l32;
    const float* xp = xrow + l32;
    float a0 = 0, a1 = 0, a2 = 0, a3 = 0;
#pragma unroll
    for (int j = 0; j < 32; j += 4) {
        a0 += xp[32 * j]       * wrow[32 * j];
        a1 += xp[32 * (j + 1)] * wrow[32 * (j + 1)];
        a2 += xp[32 * (j + 2)] * wrow[32 * (j + 2)];
        a3 += xp[32 * (j + 3)] * wrow[32 * (j + 3)];
    }
    float acc = (a0 + a1) + (a2 + a3);
#pragma unroll
    for (int o = 16; o > 0; o >>= 1) acc += __shfl_down(acc, o, 32);
    if ((tid & 31) == 0) smem[512 + e] = acc;
    __syncthreads();

    if (tid < 64) {
        float2 p0 = ((float2*)smem)[tid];
        float2 p1 = ((float2*)smem)[tid + 64];
        float2 p2 = ((float2*)smem)[tid + 128];
        float2 p3 = ((float2*)smem)[tid + 192];
        float ss = (p0.x + p1.x) + (p2.x + p3.x);
        float qq = (p0.y + p1.y) + (p2.y + p3.y);
#pragma unroll
        for (int o = 32; o > 0; o >>= 1) {
            ss += __shfl_down(ss, o);
            qq += __shfl_down(qq, o);
        }
        if (tid == 0) {
            float mu = ss * (1.f / DDIM);
            float var = qq * (1.f / DDIM) - mu * mu;
            float rstd = rsqrtf(var + 1e-5f);
            int best = 0; float bl = -3.4e38f;
            float L[8];
            for (int k = 0; k < 8; k++) {
                float l = smem[512 + k] + br[k];
                L[k] = l;
                if (l > bl) { bl = l; best = k; }   // strict > == jnp.argmax first-max
            }
            float den = 0;
            for (int k = 0; k < 8; k++) den += __expf(L[k] - bl);
            gate[t] = 1.f / den;
            expert[t] = best;
            atomicAdd(&counts[best], 1);
            smem[520] = mu; smem[521] = rstd;
        }
    }
    __syncthreads();
    float mu = smem[520], rstd = smem[521];
    float4 gg = ((const float4*)lng)[tid];
    float4 bb = ((const float4*)lnb)[tid];
    ushort4 o;
    o.x = f2bf((xv.x - mu) * rstd * gg.x + bb.x);
    o.y = f2bf((xv.y - mu) * rstd * gg.y + bb.y);
    o.z = f2bf((xv.z - mu) * rstd * gg.z + bb.z);
    o.w = f2bf((xv.w - mu) * rstd * gg.w + bb.w);
    *(ushort4*)(xn + (size_t)t * DDIM + tid * 4) = o;
}

// ---------------- scatter tokens into per-expert lists ----------------
__global__ __launch_bounds__(256) void scatter_perm(
    const int* __restrict__ expert, const int* __restrict__ counts,
    int* __restrict__ fill, int* __restrict__ perm) {
    __shared__ int offs_s[NEXP];
    if (threadIdx.x < NEXP) {
        int o = 0;
        for (int i = 0; i < (int)threadIdx.x; i++) o += counts[i];
        offs_s[threadIdx.x] = o;
    }
    __syncthreads();
    int t = blockIdx.x * 256 + threadIdx.x;
    int e = expert[t];
    int p = atomicAdd(&fill[e], 1);
    perm[offs_s[e] + p] = t;
}

// ====== GEMM0 (128x128, BK=64, swizzle) + W2-transpose fused in one grid ===
// blocks [0, G0_TILES): h_perm = relu(xn[perm] @ W1t[e]^T + b1[e])
// blocks [G0_TILES, +W2_TILES): W2 [E][4096][1024] -> W2t [E][1024][4096]
__global__ __launch_bounds__(256) void gemm0_w2t(
    const unsigned short* __restrict__ A, const unsigned short* __restrict__ Bt,
    const float* __restrict__ bias, unsigned short* __restrict__ Hout,
    const float* __restrict__ W2, unsigned short* __restrict__ W2t,
    const int* __restrict__ perm, const int* __restrict__ counts) {
    __shared__ __align__(16) unsigned short smem_u[16384];   // 32 KB
    int tid = threadIdx.x;

    if (blockIdx.x >= G0_TILES) {
        int q = blockIdx.x - G0_TILES;     // 1024 tiles/expert
        int e = q >> 10;
        int c0 = (q & 15) * 64, r0 = ((q >> 4) & 63) * 64;
        transpose_tile64((float*)smem_u, W2, W2t, FDIM, DDIM, e, r0, c0, tid);
        return;
    }

    const int K = DDIM, N = FDIM;
    int bx = blockIdx.x;
    int rem = bx >> 5;                 // m-tile slot (0..71)
    int n0 = (bx & 31) << 7;           // n-tile (32 of 128)
    int e, off = 0, cnt = 0; bool found = false;
    for (e = 0; e < NEXP; e++) {
        cnt = counts[e];
        int mt = (cnt + (BM - 1)) >> 7;
        if (rem < mt) { found = true; break; }
        rem -= mt; off += cnt;
    }
    if (!found) return;
    int mbase = rem << 7;
    int mrem = cnt - mbase;

    unsigned short* Alds = smem_u;            // 16 KB
    unsigned short* Blds = smem_u + 8192;     // 16 KB

    int lane = tid & 63, wave = tid >> 6;
    int grow = lane >> 3;
    int seg  = lane & 7;
    int gseg = seg ^ grow;

    const unsigned short* ag[4];
    unsigned short* al[4];
    const unsigned short* bg[4];
    unsigned short* bl[4];
#pragma unroll
    for (int p = 0; p < 4; p++) {
        int r = p * 32 + wave * 8 + grow;
        int rr = (r < mrem) ? r : 0;
        int t = perm[off + mbase + rr];
        ag[p] = A + (size_t)t * K + gseg * 8;
        al[p] = &Alds[(p * 32 + wave * 8) * BK];
        bg[p] = Bt + ((size_t)e * N + n0 + r) * K + gseg * 8;
        bl[p] = &Blds[(p * 32 + wave * 8) * BK];
    }

    int wr = (wave >> 1) * 64, wc = (wave & 1) * 64;
    int q = lane >> 4, l16 = lane & 15;
    int sx = l16 & 7;

    f32x4 acc[4][4] = {};

    for (int k0 = 0; k0 < K; k0 += BK) {
#pragma unroll
        for (int p = 0; p < 4; p++) async16(ag[p] + k0, al[p]);
#pragma unroll
        for (int p = 0; p < 4; p++) async16(bg[p] + k0, bl[p]);
        __syncthreads();
#pragma unroll
        for (int kk = 0; kk < 2; kk++) {
            int slot = ((kk * 4 + q) ^ sx) * 8;
            bf16x8 af[4], bfr[4];
#pragma unroll
            for (int i = 0; i < 4; i++)
                af[i] = *(const bf16x8*)&Alds[(wr + i * 16 + l16) * BK + slot];
#pragma unroll
            for (int j = 0; j < 4; j++)
                bfr[j] = *(const bf16x8*)&Blds[(wc + j * 16 + l16) * BK + slot];
#pragma unroll
            for (int i = 0; i < 4; i++)
#pragma unroll
                for (int j = 0; j < 4; j++)
                    acc[i][j] = __builtin_amdgcn_mfma_f32_16x16x32_bf16(af[i], bfr[j], acc[i][j], 0, 0, 0);
        }
        __syncthreads();
    }

    float bs[4];
#pragma unroll
    for (int j = 0; j < 4; j++) bs[j] = bias[(size_t)e * N + n0 + wc + j * 16 + l16];
#pragma unroll
    for (int i = 0; i < 4; i++) {
#pragma unroll
        for (int r = 0; r < 4; r++) {
            int lrow = wr + i * 16 + q * 4 + r;
            if (lrow < mrem) {
                unsigned short* hp = Hout + (size_t)(off + mbase + lrow) * N + n0 + wc + l16;
#pragma unroll
                for (int j = 0; j < 4; j++) {
                    float v = acc[i][j][r] + bs[j];
                    hp[j * 16] = f2bf(fmaxf(v, 0.f));
                }
            }
        }
    }
}

// ====== GEMM1 (R5 config: 128x64 tile, BK=64, swizzle, direct store) =======
__global__ __launch_bounds__(256) void gemm1(
    const unsigned short* __restrict__ A, const unsigned short* __restrict__ Bt,
    const float* __restrict__ bias, float* __restrict__ Yout,
    const float* __restrict__ gate, const int* __restrict__ perm,
    const int* __restrict__ counts) {
    const int K = FDIM, N = DDIM;
    int rem = blockIdx.x;
    int e, off = 0, cnt = 0; bool found = false;
    for (e = 0; e < NEXP; e++) {
        cnt = counts[e];
        int mt = (cnt + (BM - 1)) >> 7;
        if (rem < mt) { found = true; break; }
        rem -= mt; off += cnt;
    }
    if (!found) return;
    int mbase = rem << 7;
    int mrem = cnt - mbase;
    int n0 = blockIdx.y << 6;

    __shared__ __align__(16) unsigned short Alds[BM * BK];   // 16 KB
    __shared__ __align__(16) unsigned short Blds[64 * BK];   // 8 KB

    int tid = threadIdx.x;
    int lane = tid & 63, wave = tid >> 6;
    int grow = lane >> 3;
    int seg  = lane & 7;
    int gseg = seg ^ grow;

    const unsigned short* ag[4];
    unsigned short* al[4];
    const unsigned short* bg[2];
    unsigned short* bl[2];
#pragma unroll
    for (int p = 0; p < 4; p++) {
        int r = p * 32 + wave * 8 + grow;
        int rr = (r < mrem) ? r : 0;
        ag[p] = A + (size_t)(off + mbase + rr) * K + gseg * 8;   // h permuted
        al[p] = &Alds[(p * 32 + wave * 8) * BK];
    }
#pragma unroll
    for (int p = 0; p < 2; p++) {
        int r = p * 32 + wave * 8 + grow;
        bg[p] = Bt + ((size_t)e * N + n0 + r) * K + gseg * 8;
        bl[p] = &Blds[(p * 32 + wave * 8) * BK];
    }

    int wr = wave * 32, wc = 0;
    int q = lane >> 4, l16 = lane & 15;
    int sx = l16 & 7;

    f32x4 acc[2][4] = {};

    for (int k0 = 0; k0 < K; k0 += BK) {
#pragma unroll
        for (int p = 0; p < 4; p++) async16(ag[p] + k0, al[p]);
#pragma unroll
        for (int p = 0; p < 2; p++) async16(bg[p] + k0, bl[p]);
        __syncthreads();
#pragma unroll
        for (int kk = 0; kk < 2; kk++) {
            int slot = ((kk * 4 + q) ^ sx) * 8;
            bf16x8 af[2], bfr[4];
#pragma unroll
            for (int i = 0; i < 2; i++)
                af[i] = *(const bf16x8*)&Alds[(wr + i * 16 + l16) * BK + slot];
#pragma unroll
            for (int j = 0; j < 4; j++)
                bfr[j] = *(const bf16x8*)&Blds[(wc + j * 16 + l16) * BK + slot];
#pragma unroll
            for (int i = 0; i < 2; i++)
#pragma unroll
                for (int j = 0; j < 4; j++)
                    acc[i][j] = __builtin_amdgcn_mfma_f32_16x16x32_bf16(af[i], bfr[j], acc[i][j], 0, 0, 0);
        }
        __syncthreads();
    }

    float bs[4];
#pragma unroll
    for (int j = 0; j < 4; j++) bs[j] = bias[(size_t)e * N + n0 + wc + j * 16 + l16];
#pragma unroll
    for (int i = 0; i < 2; i++) {
#pragma unroll
        for (int r = 0; r < 4; r++) {
            int lrow = wr + i * 16 + q * 4 + r;
            if (lrow < mrem) {
                int t = perm[off + mbase + lrow];
                float gt = gate[t];
                float* yp = Yout + (size_t)t * N + n0 + wc + l16;
#pragma unroll
                for (int j = 0; j < 4; j++)
                    yp[j * 16] = (acc[i][j][r] + bs[j]) * gt;
            }
        }
    }
}

extern "C" void kernel_launch(void* const* d_in, const int* in_sizes, int n_in,
                              void* d_out, int out_size, void* d_ws, size_t ws_size,
                              hipStream_t stream) {
    const float* x   = (const float*)d_in[0];
    const float* Wr  = (const float*)d_in[1];
    const float* br  = (const float*)d_in[2];
    const float* lng = (const float*)d_in[3];
    const float* lnb = (const float*)d_in[4];
    const float* W1  = (const float*)d_in[5];
    const float* b1  = (const float*)d_in[6];
    const float* W2  = (const float*)d_in[7];
    const float* b2  = (const float*)d_in[8];
    float* out = (float*)d_out;

    char* ws = (char*)d_ws;
    size_t o = 0;
    unsigned short* W1t = (unsigned short*)(ws + o); o += (size_t)NEXP * DDIM * FDIM * 2;  // [E][F][D]
    unsigned short* W2t = (unsigned short*)(ws + o); o += (size_t)NEXP * DDIM * FDIM * 2;  // [E][D][F]
    unsigned short* xn  = (unsigned short*)(ws + o); o += (size_t)T_TOK * DDIM * 2;        // [T][D]
    unsigned short* h   = (unsigned short*)(ws + o); o += (size_t)T_TOK * FDIM * 2;        // [Tperm][F]
    float* gate = (float*)(ws + o); o += (size_t)T_TOK * 4;
    float* WrT  = (float*)(ws + o); o += (size_t)NEXP * DDIM * 4;                          // [E][D]
    int* expert = (int*)(ws + o);   o += (size_t)T_TOK * 4;
    int* perm   = (int*)(ws + o);   o += (size_t)T_TOK * 4;
    int* meta   = (int*)(ws + o);   // counts[8], fill[8]
    int* counts = meta;
    int* fill   = meta + 8;

    init_kernel<<<32, 256, 0, stream>>>(Wr, WrT, meta);
    prep<<<2 * T_TOK, 256, 0, stream>>>(x, WrT, br, lng, lnb, W1,
                                        xn, W1t, gate, expert, counts);
    scatter_perm<<<T_TOK / 256, 256, 0, stream>>>(expert, counts, fill, perm);
    gemm0_w2t<<<G0_TILES + W2_TILES, 256, 0, stream>>>(
        xn, W1t, b1, h, W2, W2t, perm, counts);
    gemm1<<<dim3(MAX_MT, DDIM / 64), 256, 0, stream>>>(
        h, W2t, b2, out, gate, perm, counts);
}